// Round 5
// baseline (98.628 us; speedup 1.0000x reference)
//
#include <hip/hip_runtime.h>

// Fused no-softmax attention block, MI355X/gfx950.
// out = LN( q + Q @ Gt_b^T + bo ),  Q = q@Wq^T+bq,
// Gt_b[n,k'] = sum_d Wo[n,h(k')*64+d] * M_bh[d',d]/8,  M_bh = K^T V  (no softmax -> exact)
// proj: m201-style 8-phase 256x256xBK64 kernel, 8 waves, 128KB LDS, counted vmcnt(6),
//       raw s_barrier pairs, setprio around MFMA, quad-XOR LDS swizzle, XCD-chunked grid.
// gemm_out: ring-3 128x128 (R4). M zeroed by cvt tail blocks.

typedef __bf16 bf16;
typedef __bf16 bf16x8 __attribute__((ext_vector_type(8)));
typedef float f32x4 __attribute__((ext_vector_type(4)));

#define MFMA16(a, b, c) __builtin_amdgcn_mfma_f32_16x16x32_bf16(a, b, c, 0, 0, 0)
#define BARRIER() asm volatile("s_barrier" ::: "memory")

template <int N>
__device__ __forceinline__ void vmcnt_wait() {
  if constexpr (N == 6) asm volatile("s_waitcnt vmcnt(6)" ::: "memory");
  else if constexpr (N == 4) asm volatile("s_waitcnt vmcnt(4)" ::: "memory");
  else if constexpr (N == 0) asm volatile("s_waitcnt vmcnt(0)" ::: "memory");
}

__device__ __forceinline__ bf16x8 ld8(const bf16* p) { return *(const bf16x8*)p; }

__device__ __forceinline__ void gload16(const void* g, void* l) {
  __builtin_amdgcn_global_load_lds((__attribute__((address_space(1))) void*)(g),
                                   (__attribute__((address_space(3))) void*)(l), 16, 0, 0);
}

__device__ __forceinline__ int swz4(int row) { return (row ^ (row >> 2)) & 3; }

// ---------------- 1. f32 -> bf16 (q,k,v,Wq,Wk,Wv) + zero M ----------------
__global__ __launch_bounds__(256) void cvt_kernel(
    const float* __restrict__ q, const float* __restrict__ k, const float* __restrict__ v,
    const float* __restrict__ wq, const float* __restrict__ wk, const float* __restrict__ wv,
    bf16* __restrict__ dst, float* __restrict__ Mz) {
  const int bid = blockIdx.x;
  if (bid >= 7680) {  // zero M: 64 blocks x 256 thr x 8 f32
    float* p = Mz + (size_t)(bid - 7680) * 2048 + threadIdx.x * 8;
    *(f32x4*)p = f32x4{0.f, 0.f, 0.f, 0.f};
    *(f32x4*)(p + 4) = f32x4{0.f, 0.f, 0.f, 0.f};
    return;
  }
  const float* s; size_t dof; int x;
  if (bid < 6144) {
    const int y = bid >> 11; x = bid & 2047;
    s = (y == 0) ? q : (y == 1 ? k : v);
    dof = (size_t)y * 4194304u;
  } else {
    const int idx = bid - 6144; const int y = idx >> 9; x = idx & 511;
    s = (y == 0) ? wq : (y == 1 ? wk : wv);
    dof = 12582912u + (size_t)y * 1048576u;
  }
  const size_t i = ((size_t)x * 256 + threadIdx.x) * 8;
  f32x4 a = *(const f32x4*)(s + i);
  f32x4 b = *(const f32x4*)(s + i + 4);
  bf16x8 o;
  o[0] = (bf16)a[0]; o[1] = (bf16)a[1]; o[2] = (bf16)a[2]; o[3] = (bf16)a[3];
  o[4] = (bf16)b[0]; o[5] = (bf16)b[1]; o[6] = (bf16)b[2]; o[7] = (bf16)b[3];
  *(bf16x8*)(dst + dof + i) = o;
}

// ---------------- 2. QKV proj: 8-phase 256x256, BK=64, 8 waves ----------------
// LDS per buf (64KB): A_k0[0,16K) A_k1[16K,32K) B_k0[32K,48K) B_k1[48K,64K); buf1 +64K.
// Units (16KB, 2 gloads/thread): u=4T+{0:A_k0,1:B_k0,2:A_k1,3:B_k1}. Issue lead 4-5 phases.
// Phase PH of tile kt: reads A frags (PH&1)*4.. at k-half (PH>>1) [+B at even PH];
// issues: P0->B_k0(kt+1), P1->A_k1(kt+1), P2->B_k1(kt+1), P3->A_k0(kt+2).
// vmcnt(6) after MFMA at P1/P3 (3 units in flight); epilogue 6->4->0.
template <int PH, int VMC, bool ISSUE>
__device__ __forceinline__ void proj_phase(
    int kt, char* lds, const bf16* gA, const bf16* gB, int widb,
    const int (&aoff)[8], const int (&boff)[4], bf16x8 (&bv)[4], f32x4 (&acc)[8][4]) {
  const int bufoff = (kt & 1) << 16;
  const int nbufoff = bufoff ^ 65536;
  constexpr int kh = (PH >> 1) & 1;
  constexpr int mh = PH & 1;
  const char* areg = lds + bufoff + kh * 16384;
  const char* breg = lds + bufoff + 32768 + kh * 16384;
  if constexpr (PH == 0 || PH == 2) {
#pragma unroll
    for (int j = 0; j < 4; j++) bv[j] = *(const bf16x8*)(breg + boff[j]);
  }
  bf16x8 av[4];
#pragma unroll
  for (int i = 0; i < 4; i++) av[i] = *(const bf16x8*)(areg + aoff[mh * 4 + i]);
  if constexpr (ISSUE) {
    const bf16* src; char* dst;
    if constexpr (PH == 0) { src = gB + (kt + 1) * 64;      dst = lds + nbufoff + 32768; }
    if constexpr (PH == 1) { src = gA + (kt + 1) * 64 + 32; dst = lds + nbufoff + 16384; }
    if constexpr (PH == 2) { src = gB + (kt + 1) * 64 + 32; dst = lds + nbufoff + 49152; }
    if constexpr (PH == 3) { src = gA + (kt + 2) * 64;      dst = lds + bufoff; }
    gload16(src, dst + widb);
    gload16(src + 131072, dst + 8192 + widb);
  }
  BARRIER();
  __builtin_amdgcn_s_setprio(1);
#pragma unroll
  for (int i = 0; i < 4; i++)
#pragma unroll
    for (int j = 0; j < 4; j++) acc[mh * 4 + i][j] = MFMA16(av[i], bv[j], acc[mh * 4 + i][j]);
  __builtin_amdgcn_s_setprio(0);
  if constexpr (VMC >= 0) vmcnt_wait<VMC>();
  BARRIER();
}

__global__ __launch_bounds__(512, 2) void gemm_proj8(
    const bf16* __restrict__ qkv, const bf16* __restrict__ Wall,
    const float* __restrict__ bq, const float* __restrict__ bk, const float* __restrict__ bv_,
    bf16* __restrict__ Call) {
  __shared__ __align__(1024) char lds[131072];
  const int wg = blockIdx.x;                 // 192 = 48 mt x 4 nt
  const int swz = (wg & 7) * 24 + (wg >> 3); // XCD-chunked, bijective (192%8==0)
  const int mt = swz >> 2, nt = swz & 3;
  const int m0 = mt * 256, n0 = nt * 256;
  const int z = mt >> 4, mbase = (mt & 15) * 256;
  const bf16* Ab = qkv + (size_t)m0 * 1024;
  const bf16* Bb = Wall + (size_t)z * 1048576u + (size_t)n0 * 1024;

  const int t = threadIdx.x;
  const int lane = t & 63, wid = t >> 6;
  const int wr = wid >> 2, wc = wid & 3;
  const int r16 = lane & 15, kg = lane >> 4;
  const int widb = wid << 10;

  // staging bases: thread t covers rows t>>2 (j=0) and 128+(t>>2) (j=1), pre-swizzled chunk
  const int srow = t >> 2;
  const int c0 = (t & 3) ^ swz4(srow);  // swz4(srow+128)==swz4(srow)
  const bf16* gA = Ab + (size_t)srow * 1024 + c0 * 8;
  const bf16* gB = Bb + (size_t)srow * 1024 + c0 * 8;

  // read offsets within a 16KB (matrix,k-half) region
  int aoff[8], boff[4];
#pragma unroll
  for (int f = 0; f < 8; f++) {
    const int row = wr * 128 + f * 16 + r16;
    aoff[f] = row * 64 + ((kg ^ swz4(row)) << 4);
  }
#pragma unroll
  for (int nf = 0; nf < 4; nf++) {
    const int row = wc * 64 + nf * 16 + r16;
    boff[nf] = row * 64 + ((kg ^ swz4(row)) << 4);
  }

  f32x4 acc[8][4] = {};
  bf16x8 bv[4];

  // prologue: units 0..4 in order A_k0(0), B_k0(0), A_k1(0), B_k1(0), A_k0(1)
  gload16(gA, lds + widb);                gload16(gA + 131072, lds + 8192 + widb);
  gload16(gB, lds + 32768 + widb);        gload16(gB + 131072, lds + 40960 + widb);
  gload16(gA + 32, lds + 16384 + widb);   gload16(gA + 131072 + 32, lds + 24576 + widb);
  gload16(gB + 32, lds + 49152 + widb);   gload16(gB + 131072 + 32, lds + 57344 + widb);
  gload16(gA + 64, lds + 65536 + widb);   gload16(gA + 131072 + 64, lds + 73728 + widb);
  vmcnt_wait<6>();  // units 0,1 landed (newest 6 loads = units 2,3,4)
  BARRIER();

  for (int kt = 0; kt < 14; kt++) {
    proj_phase<0, -1, true>(kt, lds, gA, gB, widb, aoff, boff, bv, acc);
    proj_phase<1,  6, true>(kt, lds, gA, gB, widb, aoff, boff, bv, acc);
    proj_phase<2, -1, true>(kt, lds, gA, gB, widb, aoff, boff, bv, acc);
    proj_phase<3,  6, true>(kt, lds, gA, gB, widb, aoff, boff, bv, acc);
  }
  // kt=14: last issue is B_k1(15) at P2; P3 skips (would be A_k0(16)); drain 6->4
  proj_phase<0, -1, true >(14, lds, gA, gB, widb, aoff, boff, bv, acc);
  proj_phase<1,  6, true >(14, lds, gA, gB, widb, aoff, boff, bv, acc);
  proj_phase<2, -1, true >(14, lds, gA, gB, widb, aoff, boff, bv, acc);
  proj_phase<3,  4, false>(14, lds, gA, gB, widb, aoff, boff, bv, acc);
  // kt=15: no issues; P1-end vmcnt(0) guarantees units 62,63 for P2/P3
  proj_phase<0, -1, false>(15, lds, gA, gB, widb, aoff, boff, bv, acc);
  proj_phase<1,  0, false>(15, lds, gA, gB, widb, aoff, boff, bv, acc);
  proj_phase<2, -1, false>(15, lds, gA, gB, widb, aoff, boff, bv, acc);
  proj_phase<3, -1, false>(15, lds, gA, gB, widb, aoff, boff, bv, acc);

  const float* bias = (z == 0) ? bq : (z == 1 ? bk : bv_);
  bf16* C = Call + (size_t)z * 4194304u;
#pragma unroll
  for (int nf = 0; nf < 4; nf++) {
    const int col = n0 + wc * 64 + nf * 16 + r16;
    const float bj = bias[col];
#pragma unroll
    for (int f = 0; f < 8; f++) {
      const int grow = mbase + wr * 128 + f * 16 + kg * 4;
#pragma unroll
      for (int r = 0; r < 4; r++)
        C[(size_t)(grow + r) * 1024 + col] = (bf16)(acc[f][nf][r] + bj);
    }
  }
}

// ---------------- ring-3 GEMM mainloop (gemm_out): 128x128, BK=32 ----------------
__device__ __forceinline__ void compute16(const char* buf, const int aoff[4], const int boff[4],
                                          f32x4 (&acc)[4][4]) {
  bf16x8 av[4], bv[4];
#pragma unroll
  for (int i = 0; i < 4; i++) av[i] = *(const bf16x8*)(buf + aoff[i]);
#pragma unroll
  for (int j = 0; j < 4; j++) bv[j] = *(const bf16x8*)(buf + boff[j]);
  __builtin_amdgcn_s_setprio(1);
#pragma unroll
  for (int i = 0; i < 4; i++)
#pragma unroll
    for (int j = 0; j < 4; j++) acc[i][j] = MFMA16(av[i], bv[j], acc[i][j]);
  __builtin_amdgcn_s_setprio(0);
}

__device__ __forceinline__ void ring128(const bf16* __restrict__ A, const bf16* __restrict__ B,
                                        char* lds, f32x4 (&acc)[4][4]) {
  const int t = threadIdx.x;
  const int lane = t & 63, wid = t >> 6;
  const int wr = wid >> 1, wc = wid & 1;
  const int r16 = lane & 15, kg = lane >> 4;

  int aoff[4], boff[4];
#pragma unroll
  for (int i = 0; i < 4; i++) {
    int row = wr * 64 + i * 16 + r16;
    aoff[i] = row * 64 + ((kg ^ swz4(row)) << 4);
    row = wc * 64 + i * 16 + r16;
    boff[i] = 8192 + row * 64 + ((kg ^ swz4(row)) << 4);
  }

  const int r1 = t >> 2, c = t & 3, r2 = r1 + 64;
  const bf16* pa1 = A + (size_t)r1 * 1024 + (c ^ swz4(r1)) * 8;
  const bf16* pa2 = A + (size_t)r2 * 1024 + (c ^ swz4(r2)) * 8;
  const bf16* pb1 = B + (size_t)r1 * 1024 + (c ^ swz4(r1)) * 8;
  const bf16* pb2 = B + (size_t)r2 * 1024 + (c ^ swz4(r2)) * 8;
  const int d1 = wid << 10, d2 = 4096 + (wid << 10);

#pragma unroll
  for (int p = 0; p < 2; p++) {
    char* d = lds + p * 16384;
    gload16(pa1 + p * 32, d + d1);
    gload16(pa2 + p * 32, d + d2);
    gload16(pb1 + p * 32, d + 8192 + d1);
    gload16(pb2 + p * 32, d + 8192 + d2);
  }
  pa1 += 64; pa2 += 64; pb1 += 64; pb2 += 64;

  int cb = 0, rb = 2;
  for (int kt = 0; kt < 30; kt++) {
    vmcnt_wait<4>();
    BARRIER();
    {
      char* d = lds + rb * 16384;
      gload16(pa1, d + d1);
      gload16(pa2, d + d2);
      gload16(pb1, d + 8192 + d1);
      gload16(pb2, d + 8192 + d2);
      pa1 += 32; pa2 += 32; pb1 += 32; pb2 += 32;
    }
    compute16(lds + cb * 16384, aoff, boff, acc);
    cb = (cb == 2) ? 0 : cb + 1;
    rb = (rb == 2) ? 0 : rb + 1;
  }
  vmcnt_wait<4>(); BARRIER(); compute16(lds + cb * 16384, aoff, boff, acc);
  cb = (cb == 2) ? 0 : cb + 1;
  vmcnt_wait<0>(); BARRIER(); compute16(lds + cb * 16384, aoff, boff, acc);
}

// ---------------- 3. M[b,h][i][j] += sum_s K[s,i] * V[s,j] ----------------
__global__ __launch_bounds__(256) void ktv_kernel(
    const bf16* __restrict__ Kb, const bf16* __restrict__ Vb, float* __restrict__ M) {
  const int bh = blockIdx.y, b = bh >> 4, h = bh & 15;
  const int s0 = blockIdx.x * 128;
  __shared__ bf16 Kl[64][136];
  __shared__ bf16 Vl[64][136];
  const int t = threadIdx.x;
  const size_t base = ((size_t)b * 2048 + s0) * 1024 + h * 64;
#pragma unroll
  for (int p = 0; p < 4; p++) {
    const int chunk = p * 256 + t;
    const int s = chunk >> 3, d0 = (chunk & 7) * 8;
    bf16x8 kv = ld8(Kb + base + (size_t)s * 1024 + d0);
    bf16x8 vv = ld8(Vb + base + (size_t)s * 1024 + d0);
#pragma unroll
    for (int e = 0; e < 8; e++) { Kl[d0 + e][s] = kv[e]; Vl[d0 + e][s] = vv[e]; }
  }
  __syncthreads();
  const int l = t & 63, w = t >> 6;
  const int r16 = l & 15, kg = l >> 4;
  f32x4 acc[4] = {};
#pragma unroll
  for (int ks = 0; ks < 4; ks++) {
    bf16x8 a = ld8(&Kl[w * 16 + r16][ks * 32 + kg * 8]);
#pragma unroll
    for (int j = 0; j < 4; j++) {
      bf16x8 bvv = ld8(&Vl[j * 16 + r16][ks * 32 + kg * 8]);
      acc[j] = MFMA16(a, bvv, acc[j]);
    }
  }
  float* Mh = M + (size_t)bh * 4096;
#pragma unroll
  for (int j = 0; j < 4; j++)
#pragma unroll
    for (int r = 0; r < 4; r++)
      atomicAdd(&Mh[(w * 16 + kg * 4 + r) * 64 + j * 16 + r16], acc[j][r]);
}

// ---------------- 4. Gt[b][n][h*64+d'] = sum_d Wo[n,h*64+d](f32) * M_bh[d',d]/8 ----------------
__global__ __launch_bounds__(256) void gt_kernel(
    const float* __restrict__ Wo, const float* __restrict__ M, bf16* __restrict__ Gt) {
  const int bid = blockIdx.x;
  const int b = bid >> 7, h = (bid >> 3) & 15, nt = bid & 7;
  const int n0 = nt * 128;
  const float* Mh = M + (size_t)((b << 4) + h) * 4096;
  const int l = threadIdx.x & 63, w = threadIdx.x >> 6;
  const int r16 = l & 15, kg = l >> 4;
  f32x4 acc[2][4] = {};
#pragma unroll
  for (int kk = 0; kk < 2; kk++) {
    bf16x8 a[2];
#pragma unroll
    for (int i = 0; i < 2; i++) {
      const float* wp = Wo + (size_t)(n0 + w * 32 + i * 16 + r16) * 1024 + h * 64 + kk * 32 + kg * 8;
      f32x4 lo = *(const f32x4*)wp;
      f32x4 hi = *(const f32x4*)(wp + 4);
      a[i][0] = (bf16)lo[0]; a[i][1] = (bf16)lo[1]; a[i][2] = (bf16)lo[2]; a[i][3] = (bf16)lo[3];
      a[i][4] = (bf16)hi[0]; a[i][5] = (bf16)hi[1]; a[i][6] = (bf16)hi[2]; a[i][7] = (bf16)hi[3];
    }
#pragma unroll
    for (int j = 0; j < 4; j++) {
      const float* mp = Mh + (j * 16 + r16) * 64 + kk * 32 + kg * 8;
      f32x4 m0v = *(const f32x4*)mp;
      f32x4 m1v = *(const f32x4*)(mp + 4);
      bf16x8 bv;
      bv[0] = (bf16)(m0v[0] * 0.125f); bv[1] = (bf16)(m0v[1] * 0.125f);
      bv[2] = (bf16)(m0v[2] * 0.125f); bv[3] = (bf16)(m0v[3] * 0.125f);
      bv[4] = (bf16)(m1v[0] * 0.125f); bv[5] = (bf16)(m1v[1] * 0.125f);
      bv[6] = (bf16)(m1v[2] * 0.125f); bv[7] = (bf16)(m1v[3] * 0.125f);
#pragma unroll
      for (int i = 0; i < 2; i++) acc[i][j] = MFMA16(a[i], bv, acc[i][j]);
    }
  }
  bf16* G = Gt + (size_t)b * 1048576u;
#pragma unroll
  for (int i = 0; i < 2; i++)
#pragma unroll
    for (int j = 0; j < 4; j++)
#pragma unroll
      for (int r = 0; r < 4; r++)
        G[(size_t)(n0 + w * 32 + i * 16 + kg * 4 + r) * 1024 + h * 64 + j * 16 + r16] =
            (bf16)acc[i][j][r];
}

// ---------------- 5. out = resid + Q @ Gt_b^T + bo (f32) ----------------
__global__ __launch_bounds__(256, 3) void gemm_out_r(
    const bf16* __restrict__ Q, const bf16* __restrict__ Gt,
    const float* __restrict__ bo, const float* __restrict__ resid, float* __restrict__ out) {
  __shared__ __align__(1024) char lds[49152];
  const int wg = blockIdx.x;                 // 256 = 32 mt x 8 nt
  const int swz = (wg & 7) * 32 + (wg >> 3);
  const int mt = swz >> 3, nt = swz & 7;
  const int m0 = mt * 128, n0 = nt * 128;

  f32x4 acc[4][4] = {};
  ring128(Q + (size_t)m0 * 1024, Gt + (size_t)(m0 >> 11) * 1048576u + (size_t)n0 * 1024, lds, acc);

  const int lane = threadIdx.x & 63, wid = threadIdx.x >> 6;
  const int wr = wid >> 1, wc = wid & 1, r16 = lane & 15, kg = lane >> 4;
#pragma unroll
  for (int j = 0; j < 4; j++) {
    const int col = n0 + wc * 64 + j * 16 + r16;
    const float bj = bo[col];
#pragma unroll
    for (int i = 0; i < 4; i++) {
      const int row = m0 + wr * 64 + i * 16 + kg * 4;
#pragma unroll
      for (int r = 0; r < 4; r++) {
        const size_t off = (size_t)(row + r) * 1024 + col;
        out[off] = acc[i][j][r] + bj + resid[off];
      }
    }
  }
}

// ---------------- 6. LayerNorm: one row per wave ----------------
__global__ __launch_bounds__(256) void ln_kernel(
    float* __restrict__ x, const float* __restrict__ g, const float* __restrict__ bb) {
  const int lane = threadIdx.x & 63, wid = threadIdx.x >> 6;
  const int row = (blockIdx.x << 2) + wid;
  float* xr = x + (size_t)row * 1024;
  f32x4 v[4];
  float s = 0.f, s2 = 0.f;
#pragma unroll
  for (int e = 0; e < 4; e++) {
    v[e] = *(const f32x4*)(xr + lane * 16 + e * 4);
#pragma unroll
    for (int u = 0; u < 4; u++) { s += v[e][u]; s2 += v[e][u] * v[e][u]; }
  }
#pragma unroll
  for (int m = 32; m; m >>= 1) { s += __shfl_xor(s, m); s2 += __shfl_xor(s2, m); }
  const float mu = s * (1.0f / 1024.0f);
  const float rstd = rsqrtf(s2 * (1.0f / 1024.0f) - mu * mu + 1e-5f);
#pragma unroll
  for (int e = 0; e < 4; e++) {
    f32x4 gg = *(const f32x4*)(g + lane * 16 + e * 4);
    f32x4 bv = *(const f32x4*)(bb + lane * 16 + e * 4);
    f32x4 o;
#pragma unroll
    for (int u = 0; u < 4; u++) o[u] = gg[u] * ((v[e][u] - mu) * rstd) + bv[u];
    *(f32x4*)(xr + lane * 16 + e * 4) = o;
  }
}

extern "C" void kernel_launch(void* const* d_in, const int* in_sizes, int n_in,
                              void* d_out, int out_size, void* d_ws, size_t ws_size,
                              hipStream_t stream) {
  (void)in_sizes; (void)n_in; (void)out_size; (void)ws_size;
  const float* q    = (const float*)d_in[0];
  const float* k    = (const float*)d_in[1];
  const float* v    = (const float*)d_in[2];
  // d_in[3]=mask (all False), d_in[4]=training: unused
  const float* wq_w = (const float*)d_in[5];
  const float* wq_b = (const float*)d_in[6];
  const float* wk_w = (const float*)d_in[7];
  const float* wk_b = (const float*)d_in[8];
  const float* wv_w = (const float*)d_in[9];
  const float* wv_b = (const float*)d_in[10];
  const float* wo_w = (const float*)d_in[11];
  const float* wo_b = (const float*)d_in[12];
  const float* ln_g = (const float*)d_in[13];
  const float* ln_b = (const float*)d_in[14];
  float* out = (float*)d_out;

  bf16* wsb    = (bf16*)d_ws;
  bf16* qkv_bf = wsb;                        // [0 .. 12582912) q,k,v bf16 (dead after proj)
  bf16* w_bf   = wsb + 12582912u;            // Wq,Wk,Wv bf16
  bf16* QKV_bf = wsb + 15728640u;            // Q,K,V bf16
  float* M     = (float*)(wsb + 28311552u);  // 131072 f32
  bf16* Gt     = wsb;                        // alias dead q region

  cvt_kernel<<<7744, 256, 0, stream>>>(q, k, v, wq_w, wk_w, wv_w, qkv_bf, M);
  gemm_proj8<<<192, 512, 0, stream>>>(qkv_bf, w_bf, wq_b, wk_b, wv_b, QKV_bf);
  ktv_kernel<<<dim3(16, 32), 256, 0, stream>>>(QKV_bf + 4194304u, QKV_bf + 8388608u, M);
  gt_kernel<<<256, 256, 0, stream>>>(wo_w, M, Gt);
  gemm_out_r<<<256, 256, 0, stream>>>(QKV_bf, Gt, wo_b, q, out);
  ln_kernel<<<1024, 256, 0, stream>>>(out, ln_g, ln_b);
}

// Round 6
// 94.103 us; speedup vs baseline: 1.0481x; 1.0481x over previous
//
#include <hip/hip_runtime.h>

// Fused no-softmax attention block, MI355X/gfx950.
// out = LN( q + Q @ Gt_b^T + bo ),  Q = q@Wq^T+bq,
// Gt_b[n,k'] = sum_d Wo[n,h(k')*64+d] * M_bh[d',d]/8,  M_bh = K^T V  (no softmax -> exact)
// R6: qkv f32->bf16 conversion FUSED into proj (reg-staged A, ds_write swizzled;
//     B via global_load_lds ring-3, counted vmcnt(2) - newest B-tile always in flight).
//     cvt is weights-only. ktv: 128 blocks, reg-accum over 4 subtiles. x stored bf16.

typedef __bf16 bf16;
typedef __bf16 bf16x8 __attribute__((ext_vector_type(8)));
typedef float f32x4 __attribute__((ext_vector_type(4)));

#define MFMA16(a, b, c) __builtin_amdgcn_mfma_f32_16x16x32_bf16(a, b, c, 0, 0, 0)
#define BARRIER() asm volatile("s_barrier" ::: "memory")
#define VMCNT2() asm volatile("s_waitcnt vmcnt(2)" ::: "memory")
#define VMCNT0() asm volatile("s_waitcnt vmcnt(0)" ::: "memory")
#define LGKM0()                                        \
  do {                                                 \
    asm volatile("s_waitcnt lgkmcnt(0)" ::: "memory"); \
    __builtin_amdgcn_sched_barrier(0);                 \
  } while (0)

__device__ __forceinline__ bf16x8 ld8(const bf16* p) { return *(const bf16x8*)p; }

__device__ __forceinline__ void gload16(const void* g, void* l) {
  __builtin_amdgcn_global_load_lds((__attribute__((address_space(1))) void*)(g),
                                   (__attribute__((address_space(3))) void*)(l), 16, 0, 0);
}

__device__ __forceinline__ int swz4(int row) { return (row ^ (row >> 2)) & 3; }

// ---------------- 1. weights f32 -> bf16 + zero M ----------------
__global__ __launch_bounds__(256) void wcvt_kernel(
    const float* __restrict__ wq, const float* __restrict__ wk, const float* __restrict__ wv,
    bf16* __restrict__ dst, float* __restrict__ Mz) {
  const int bid = blockIdx.x;
  if (bid >= 1536) {  // zero M: 64 blocks x 256 thr x 8 f32
    float* p = Mz + (size_t)(bid - 1536) * 2048 + threadIdx.x * 8;
    *(f32x4*)p = f32x4{0.f, 0.f, 0.f, 0.f};
    *(f32x4*)(p + 4) = f32x4{0.f, 0.f, 0.f, 0.f};
    return;
  }
  const int y = bid >> 9, x = bid & 511;
  const float* s = (y == 0) ? wq : (y == 1 ? wk : wv);
  const size_t i = ((size_t)x * 256 + threadIdx.x) * 8;
  f32x4 a = *(const f32x4*)(s + i);
  f32x4 b = *(const f32x4*)(s + i + 4);
  bf16x8 o;
  o[0] = (bf16)a[0]; o[1] = (bf16)a[1]; o[2] = (bf16)a[2]; o[3] = (bf16)a[3];
  o[4] = (bf16)b[0]; o[5] = (bf16)b[1]; o[6] = (bf16)b[2]; o[7] = (bf16)b[3];
  *(bf16x8*)(dst + (size_t)y * 1048576u + i) = o;
}

// ---------------- 2. QKV proj: C = A(f32)@W^T + bias, cvt fused ----------------
// 128x128 tile, BK=32, 4 waves (2x2, 64x64 each). A: reg-staged f32->bf16 (ring-3 LDS
// bufs at 0/8K/16K). B: global_load_lds ring-3 (bufs at 24K+{0,8K,16K}). 48KB -> 3 blk/CU.
__global__ __launch_bounds__(256, 3) void gemm_proj_a(
    const float* __restrict__ q, const float* __restrict__ k, const float* __restrict__ v,
    const bf16* __restrict__ Wall,
    const float* __restrict__ bq, const float* __restrict__ bk, const float* __restrict__ bv,
    bf16* __restrict__ Call) {
  __shared__ __align__(1024) char lds[49152];
  const int wg = blockIdx.x;                   // 768 = 96 mt x 8 nt
  const int swz = (wg & 7) * 96 + (wg >> 3);   // XCD-chunked, bijective (768%8==0)
  const int mt = swz >> 3, nt = swz & 7;
  const int z = mt >> 5;
  const int mloc = (mt & 31) * 128;
  const int n0 = nt * 128;
  const float* As = (z == 0) ? q : (z == 1 ? k : v);
  const bf16* W = Wall + (size_t)z * 1048576u + (size_t)n0 * 1024;

  const int t = threadIdx.x;
  const int lane = t & 63, wid = t >> 6;
  const int wr = wid >> 1, wc = wid & 1;
  const int r16 = lane & 15, kg = lane >> 4;

  int aoff[4], boff[4];
#pragma unroll
  for (int i = 0; i < 4; i++) {
    const int arow = wr * 64 + i * 16 + r16;
    aoff[i] = arow * 64 + ((kg ^ swz4(arow)) << 4);
    const int brow = wc * 64 + i * 16 + r16;
    boff[i] = brow * 64 + ((kg ^ swz4(brow)) << 4);
  }

  // A reg-staging: thread t covers row ar = t>>1, f32 cols (t&1)*16 .. +16
  const int ar = t >> 1;
  const float* Arow = As + (size_t)(mloc + ar) * 1024 + (t & 1) * 16;
  const int ws0 = ar * 64 + (((((t & 1) << 1) | 0) ^ swz4(ar)) << 4);
  const int ws1 = ar * 64 + (((((t & 1) << 1) | 1) ^ swz4(ar)) << 4);

  // B staging via gload16: chunks t and t+256 (row=c>>2, slot=c&3, pre-swizzled src)
  const int c1 = t, c2 = t + 256;
  const bf16* pb1 = W + (size_t)(c1 >> 2) * 1024 + ((c1 & 3) ^ swz4(c1 >> 2)) * 8;
  const bf16* pb2 = W + (size_t)(c2 >> 2) * 1024 + ((c2 & 3) ^ swz4(c2 >> 2)) * 8;
  const int bd1 = wid << 10, bd2 = 4096 + (wid << 10);

  f32x4 rg0, rg1, rg2, rg3;
  f32x4 acc[4][4] = {};

  // prologue: A(0) regs; B(0)->buf0, B(1)->buf1; write A(0)->buf0; A(1) regs
  {
    const float* p = Arow;
    rg0 = *(const f32x4*)p; rg1 = *(const f32x4*)(p + 4);
    rg2 = *(const f32x4*)(p + 8); rg3 = *(const f32x4*)(p + 12);
  }
  gload16(pb1, lds + 24576 + bd1);
  gload16(pb2, lds + 24576 + bd2);
  gload16(pb1 + 32, lds + 24576 + 8192 + bd1);
  gload16(pb2 + 32, lds + 24576 + 8192 + bd2);
  {
    bf16x8 p0, p1;
    p0[0] = (bf16)rg0[0]; p0[1] = (bf16)rg0[1]; p0[2] = (bf16)rg0[2]; p0[3] = (bf16)rg0[3];
    p0[4] = (bf16)rg1[0]; p0[5] = (bf16)rg1[1]; p0[6] = (bf16)rg1[2]; p0[7] = (bf16)rg1[3];
    p1[0] = (bf16)rg2[0]; p1[1] = (bf16)rg2[1]; p1[2] = (bf16)rg2[2]; p1[3] = (bf16)rg2[3];
    p1[4] = (bf16)rg3[0]; p1[5] = (bf16)rg3[1]; p1[6] = (bf16)rg3[2]; p1[7] = (bf16)rg3[3];
    *(bf16x8*)(lds + ws0) = p0;
    *(bf16x8*)(lds + ws1) = p1;
  }
  {
    const float* p = Arow + 32;
    rg0 = *(const f32x4*)p; rg1 = *(const f32x4*)(p + 4);
    rg2 = *(const f32x4*)(p + 8); rg3 = *(const f32x4*)(p + 12);
  }
  LGKM0();   // A(0) ds_writes drained
  VMCNT2();  // B(0) landed (newest-2 = B(1) stays in flight)
  BARRIER();

  int cb = 0;  // ring-3 buffer index = kt % 3
  for (int kt = 0; kt < 32; ++kt) {
    const char* la = lds + cb * 8192;
    const char* lb = lds + 24576 + cb * 8192;
    bf16x8 av[4], bw[4];
#pragma unroll
    for (int i = 0; i < 4; i++) av[i] = *(const bf16x8*)(la + aoff[i]);
#pragma unroll
    for (int j = 0; j < 4; j++) bw[j] = *(const bf16x8*)(lb + boff[j]);

    const int nb = (cb == 2) ? 0 : cb + 1;   // buf for tile kt+1 (A write)
    const int pbuf = (nb == 2) ? 0 : nb + 1; // buf for tile kt+2 (B gload)
    if (kt < 31) {  // ds_write A(kt+1) from regs loaded last iter
      bf16x8 p0, p1;
      p0[0] = (bf16)rg0[0]; p0[1] = (bf16)rg0[1]; p0[2] = (bf16)rg0[2]; p0[3] = (bf16)rg0[3];
      p0[4] = (bf16)rg1[0]; p0[5] = (bf16)rg1[1]; p0[6] = (bf16)rg1[2]; p0[7] = (bf16)rg1[3];
      p1[0] = (bf16)rg2[0]; p1[1] = (bf16)rg2[1]; p1[2] = (bf16)rg2[2]; p1[3] = (bf16)rg2[3];
      p1[4] = (bf16)rg3[0]; p1[5] = (bf16)rg3[1]; p1[6] = (bf16)rg3[2]; p1[7] = (bf16)rg3[3];
      *(bf16x8*)(lds + nb * 8192 + ws0) = p0;
      *(bf16x8*)(lds + nb * 8192 + ws1) = p1;
    }
    if (kt < 30) {  // prefetch tile kt+2: A regs + B gloads
      const float* p = Arow + (kt + 2) * 32;
      rg0 = *(const f32x4*)p; rg1 = *(const f32x4*)(p + 4);
      rg2 = *(const f32x4*)(p + 8); rg3 = *(const f32x4*)(p + 12);
      gload16(pb1 + (kt + 2) * 32, lds + 24576 + pbuf * 8192 + bd1);
      gload16(pb2 + (kt + 2) * 32, lds + 24576 + pbuf * 8192 + bd2);
    }
    __builtin_amdgcn_s_setprio(1);
#pragma unroll
    for (int i = 0; i < 4; i++)
#pragma unroll
      for (int j = 0; j < 4; j++) acc[i][j] = MFMA16(av[i], bw[j], acc[i][j]);
    __builtin_amdgcn_s_setprio(0);
    LGKM0();  // my ds_writes (and reads) drained before barrier
    if (kt < 30) { VMCNT2(); BARRIER(); }       // B(kt+1) landed; B(kt+2) in flight
    else if (kt == 30) { VMCNT0(); BARRIER(); } // B(31) landed
    cb = nb;
  }

  const float* bias = (z == 0) ? bq : (z == 1 ? bk : bv);
  bf16* C = Call + (size_t)z * 4194304u;
#pragma unroll
  for (int j = 0; j < 4; j++) {
    const int col = n0 + wc * 64 + j * 16 + r16;
    const float bj = bias[col];
#pragma unroll
    for (int i = 0; i < 4; i++) {
      const int row = mloc + wr * 64 + i * 16 + kg * 4;
#pragma unroll
      for (int r = 0; r < 4; r++)
        C[(size_t)(row + r) * 1024 + col] = (bf16)(acc[i][j][r] + bj);
    }
  }
}

// ---------------- ring-3 bf16 GEMM loop (gemm_out) ----------------
__device__ __forceinline__ void compute16(const char* la, const char* lb,
                                          const int aoff[4], const int boff[4],
                                          f32x4 (&acc)[4][4]) {
  bf16x8 av[4], bv[4];
#pragma unroll
  for (int i = 0; i < 4; i++) av[i] = *(const bf16x8*)(la + aoff[i]);
#pragma unroll
  for (int j = 0; j < 4; j++) bv[j] = *(const bf16x8*)(lb + boff[j]);
  __builtin_amdgcn_s_setprio(1);
#pragma unroll
  for (int i = 0; i < 4; i++)
#pragma unroll
    for (int j = 0; j < 4; j++) acc[i][j] = MFMA16(av[i], bv[j], acc[i][j]);
  __builtin_amdgcn_s_setprio(0);
}

__device__ __forceinline__ void ring128(const bf16* __restrict__ A, const bf16* __restrict__ B,
                                        char* lds, f32x4 (&acc)[4][4]) {
  const int t = threadIdx.x;
  const int lane = t & 63, wid = t >> 6;
  const int wr = wid >> 1, wc = wid & 1;
  const int r16 = lane & 15, kg = lane >> 4;

  int aoff[4], boff[4];
#pragma unroll
  for (int i = 0; i < 4; i++) {
    int row = wr * 64 + i * 16 + r16;
    aoff[i] = row * 64 + ((kg ^ swz4(row)) << 4);
    row = wc * 64 + i * 16 + r16;
    boff[i] = 8192 + row * 64 + ((kg ^ swz4(row)) << 4);
  }

  const int r1 = t >> 2, c = t & 3, r2 = r1 + 64;
  const bf16* pa1 = A + (size_t)r1 * 1024 + (c ^ swz4(r1)) * 8;
  const bf16* pa2 = A + (size_t)r2 * 1024 + (c ^ swz4(r2)) * 8;
  const bf16* pb1 = B + (size_t)r1 * 1024 + (c ^ swz4(r1)) * 8;
  const bf16* pb2 = B + (size_t)r2 * 1024 + (c ^ swz4(r2)) * 8;
  const int d1 = wid << 10, d2 = 4096 + (wid << 10);

#pragma unroll
  for (int p = 0; p < 2; p++) {
    char* d = lds + p * 16384;
    gload16(pa1 + p * 32, d + d1);
    gload16(pa2 + p * 32, d + d2);
    gload16(pb1 + p * 32, d + 8192 + d1);
    gload16(pb2 + p * 32, d + 8192 + d2);
  }
  pa1 += 64; pa2 += 64; pb1 += 64; pb2 += 64;

  int cb = 0, rb = 2;
  for (int kt = 0; kt < 30; kt++) {
    asm volatile("s_waitcnt vmcnt(4)" ::: "memory");
    BARRIER();
    {
      char* d = lds + rb * 16384;
      gload16(pa1, d + d1);
      gload16(pa2, d + d2);
      gload16(pb1, d + 8192 + d1);
      gload16(pb2, d + 8192 + d2);
      pa1 += 32; pa2 += 32; pb1 += 32; pb2 += 32;
    }
    compute16(lds + cb * 16384, lds + cb * 16384, aoff, boff, acc);
    LGKM0();
    cb = (cb == 2) ? 0 : cb + 1;
    rb = (rb == 2) ? 0 : rb + 1;
  }
  asm volatile("s_waitcnt vmcnt(4)" ::: "memory");
  BARRIER();
  compute16(lds + cb * 16384, lds + cb * 16384, aoff, boff, acc);
  LGKM0();
  cb = (cb == 2) ? 0 : cb + 1;
  VMCNT0(); BARRIER();
  compute16(lds + cb * 16384, lds + cb * 16384, aoff, boff, acc);
}

// ---------------- 3. M[b,h][i][j] += sum_s K[s,i] * V[s,j] (4 subtiles/block) ----------------
__global__ __launch_bounds__(256) void ktv_kernel(
    const bf16* __restrict__ Kb, const bf16* __restrict__ Vb, float* __restrict__ M) {
  const int bh = blockIdx.x >> 2, sc = blockIdx.x & 3;
  const int b = bh >> 4, h = bh & 15;
  __shared__ bf16 Kl[64][136];
  __shared__ bf16 Vl[64][136];
  const int t = threadIdx.x;
  const int l = t & 63, w = t >> 6;
  const int r16 = l & 15, kg = l >> 4;
  f32x4 acc[4] = {};
  for (int sub = 0; sub < 4; ++sub) {
    const int s0 = sc * 512 + sub * 128;
    const size_t base = ((size_t)b * 2048 + s0) * 1024 + h * 64;
    if (sub) __syncthreads();
#pragma unroll
    for (int p = 0; p < 4; p++) {
      const int chunk = p * 256 + t;
      const int s = chunk >> 3, d0 = (chunk & 7) * 8;
      bf16x8 kv = ld8(Kb + base + (size_t)s * 1024 + d0);
      bf16x8 vv = ld8(Vb + base + (size_t)s * 1024 + d0);
#pragma unroll
      for (int e = 0; e < 8; e++) { Kl[d0 + e][s] = kv[e]; Vl[d0 + e][s] = vv[e]; }
    }
    __syncthreads();
#pragma unroll
    for (int ks = 0; ks < 4; ks++) {
      bf16x8 a = ld8(&Kl[w * 16 + r16][ks * 32 + kg * 8]);
#pragma unroll
      for (int j = 0; j < 4; j++) {
        bf16x8 bvv = ld8(&Vl[j * 16 + r16][ks * 32 + kg * 8]);
        acc[j] = MFMA16(a, bvv, acc[j]);
      }
    }
  }
  float* Mh = M + (size_t)bh * 4096;
#pragma unroll
  for (int j = 0; j < 4; j++)
#pragma unroll
    for (int r = 0; r < 4; r++)
      atomicAdd(&Mh[(w * 16 + kg * 4 + r) * 64 + j * 16 + r16], acc[j][r]);
}

// ---------------- 4. Gt[b][n][h*64+d'] = sum_d Wo[n,h*64+d](f32) * M_bh[d',d]/8 ----------------
__global__ __launch_bounds__(256) void gt_kernel(
    const float* __restrict__ Wo, const float* __restrict__ M, bf16* __restrict__ Gt) {
  const int bid = blockIdx.x;
  const int b = bid >> 7, h = (bid >> 3) & 15, nt = bid & 7;
  const int n0 = nt * 128;
  const float* Mh = M + (size_t)((b << 4) + h) * 4096;
  const int l = threadIdx.x & 63, w = threadIdx.x >> 6;
  const int r16 = l & 15, kg = l >> 4;
  f32x4 acc[2][4] = {};
#pragma unroll
  for (int kk = 0; kk < 2; kk++) {
    bf16x8 a[2];
#pragma unroll
    for (int i = 0; i < 2; i++) {
      const float* wp = Wo + (size_t)(n0 + w * 32 + i * 16 + r16) * 1024 + h * 64 + kk * 32 + kg * 8;
      f32x4 lo = *(const f32x4*)wp;
      f32x4 hi = *(const f32x4*)(wp + 4);
      a[i][0] = (bf16)lo[0]; a[i][1] = (bf16)lo[1]; a[i][2] = (bf16)lo[2]; a[i][3] = (bf16)lo[3];
      a[i][4] = (bf16)hi[0]; a[i][5] = (bf16)hi[1]; a[i][6] = (bf16)hi[2]; a[i][7] = (bf16)hi[3];
    }
#pragma unroll
    for (int j = 0; j < 4; j++) {
      const float* mp = Mh + (j * 16 + r16) * 64 + kk * 32 + kg * 8;
      f32x4 m0v = *(const f32x4*)mp;
      f32x4 m1v = *(const f32x4*)(mp + 4);
      bf16x8 bv;
      bv[0] = (bf16)(m0v[0] * 0.125f); bv[1] = (bf16)(m0v[1] * 0.125f);
      bv[2] = (bf16)(m0v[2] * 0.125f); bv[3] = (bf16)(m0v[3] * 0.125f);
      bv[4] = (bf16)(m1v[0] * 0.125f); bv[5] = (bf16)(m1v[1] * 0.125f);
      bv[6] = (bf16)(m1v[2] * 0.125f); bv[7] = (bf16)(m1v[3] * 0.125f);
#pragma unroll
      for (int i = 0; i < 2; i++) acc[i][j] = MFMA16(a[i], bv, acc[i][j]);
    }
  }
  bf16* G = Gt + (size_t)b * 1048576u;
#pragma unroll
  for (int i = 0; i < 2; i++)
#pragma unroll
    for (int j = 0; j < 4; j++)
#pragma unroll
      for (int r = 0; r < 4; r++)
        G[(size_t)(n0 + w * 32 + i * 16 + kg * 4 + r) * 1024 + h * 64 + j * 16 + r16] =
            (bf16)acc[i][j][r];
}

// ---------------- 5. x = resid + Q @ Gt_b^T + bo  -> bf16 ws ----------------
__global__ __launch_bounds__(256, 3) void gemm_out_r(
    const bf16* __restrict__ Q, const bf16* __restrict__ Gt,
    const float* __restrict__ bo, const float* __restrict__ resid, bf16* __restrict__ xb) {
  __shared__ __align__(1024) char lds[49152];
  const int wg = blockIdx.x;                 // 256 = 32 mt x 8 nt
  const int swz = (wg & 7) * 32 + (wg >> 3);
  const int mt = swz >> 3, nt = swz & 7;
  const int m0 = mt * 128, n0 = nt * 128;

  f32x4 acc[4][4] = {};
  ring128(Q + (size_t)m0 * 1024, Gt + (size_t)(m0 >> 11) * 1048576u + (size_t)n0 * 1024, lds, acc);

  const int lane = threadIdx.x & 63, wid = threadIdx.x >> 6;
  const int wr = wid >> 1, wc = wid & 1, r16 = lane & 15, kg = lane >> 4;
#pragma unroll
  for (int j = 0; j < 4; j++) {
    const int col = n0 + wc * 64 + j * 16 + r16;
    const float bj = bo[col];
#pragma unroll
    for (int i = 0; i < 4; i++) {
      const int row = m0 + wr * 64 + i * 16 + kg * 4;
#pragma unroll
      for (int r = 0; r < 4; r++) {
        const size_t off = (size_t)(row + r) * 1024 + col;
        xb[off] = (bf16)(acc[i][j][r] + bj + resid[off]);
      }
    }
  }
}

// ---------------- 6. LayerNorm: x bf16 -> out f32, one row per wave ----------------
__global__ __launch_bounds__(256) void ln_kernel(
    const bf16* __restrict__ xb, const float* __restrict__ g, const float* __restrict__ bb,
    float* __restrict__ out) {
  const int lane = threadIdx.x & 63, wid = threadIdx.x >> 6;
  const int row = (blockIdx.x << 2) + wid;
  const bf16* xr = xb + (size_t)row * 1024;
  bf16x8 h0 = ld8(xr + lane * 16);
  bf16x8 h1 = ld8(xr + lane * 16 + 8);
  float v[16];
#pragma unroll
  for (int e = 0; e < 8; e++) { v[e] = (float)h0[e]; v[8 + e] = (float)h1[e]; }
  float s = 0.f, s2 = 0.f;
#pragma unroll
  for (int e = 0; e < 16; e++) { s += v[e]; s2 += v[e] * v[e]; }
#pragma unroll
  for (int m = 32; m; m >>= 1) { s += __shfl_xor(s, m); s2 += __shfl_xor(s2, m); }
  const float mu = s * (1.0f / 1024.0f);
  const float rstd = rsqrtf(s2 * (1.0f / 1024.0f) - mu * mu + 1e-5f);
  float* orow = out + (size_t)row * 1024 + lane * 16;
#pragma unroll
  for (int e = 0; e < 4; e++) {
    f32x4 gg = *(const f32x4*)(g + lane * 16 + e * 4);
    f32x4 bv = *(const f32x4*)(bb + lane * 16 + e * 4);
    f32x4 o;
#pragma unroll
    for (int u = 0; u < 4; u++) o[u] = gg[u] * ((v[e * 4 + u] - mu) * rstd) + bv[u];
    *(f32x4*)(orow + e * 4) = o;
  }
}

extern "C" void kernel_launch(void* const* d_in, const int* in_sizes, int n_in,
                              void* d_out, int out_size, void* d_ws, size_t ws_size,
                              hipStream_t stream) {
  (void)in_sizes; (void)n_in; (void)out_size; (void)ws_size;
  const float* q    = (const float*)d_in[0];
  const float* k    = (const float*)d_in[1];
  const float* v    = (const float*)d_in[2];
  // d_in[3]=mask (all False), d_in[4]=training: unused
  const float* wq_w = (const float*)d_in[5];
  const float* wq_b = (const float*)d_in[6];
  const float* wk_w = (const float*)d_in[7];
  const float* wk_b = (const float*)d_in[8];
  const float* wv_w = (const float*)d_in[9];
  const float* wv_b = (const float*)d_in[10];
  const float* wo_w = (const float*)d_in[11];
  const float* wo_b = (const float*)d_in[12];
  const float* ln_g = (const float*)d_in[13];
  const float* ln_b = (const float*)d_in[14];
  float* out = (float*)d_out;

  bf16* wsb    = (bf16*)d_ws;
  bf16* w_bf   = wsb;                        // [0, 3145728) Wq,Wk,Wv bf16
  bf16* QKV_bf = wsb + 3145728u;             // [3145728, 15728640) Q,K,V bf16
  float* M     = (float*)(wsb + 15728640u);  // 131072 f32 (512 KiB)
  bf16* Gt     = wsb + 15990784u;            // 2,097,152 elems
  bf16* xb     = wsb + 18087936u;            // 4,194,304 elems (pre-LN x, bf16)

  wcvt_kernel<<<1600, 256, 0, stream>>>(wq_w, wk_w, wv_w, w_bf, M);
  gemm_proj_a<<<768, 256, 0, stream>>>(q, k, v, w_bf, wq_b, wk_b, wv_b, QKV_bf);
  ktv_kernel<<<128, 256, 0, stream>>>(QKV_bf + 4194304u, QKV_bf + 8388608u, M);
  gt_kernel<<<256, 256, 0, stream>>>(wo_w, M, Gt);
  gemm_out_r<<<256, 256, 0, stream>>>(QKV_bf, Gt, wo_b, q, xb);
  ln_kernel<<<1024, 256, 0, stream>>>(xb, ln_g, ln_b, out);
}

// Round 7
// 93.020 us; speedup vs baseline: 1.0603x; 1.0117x over previous
//
#include <hip/hip_runtime.h>

// Fused no-softmax attention block, MI355X/gfx950.
// out = LN( q + Q @ Gt_b^T + bo ),  Q = q@Wq^T+bq,
// Gt_b[n,k'] = sum_d Wo[n,h(k')*64+d] * M_bh[d',d]/8,  M_bh = K^T V  (no softmax -> exact)
// R7: fixed vmcnt ledger in fused proj. Issue order per K-step (pinned by sched_barrier):
//   ds_write A(kt+1) [implicit vmcnt(2) for A-regs] ; 4 flat A-loads(kt+2) ; SB(0) ;
//   2 B-gloads(kt+2) ; MFMA ; lgkmcnt(0) ; vmcnt(6) ; s_barrier.
// All 6 vmem ops/iter counted: vmcnt(6) retires exactly B(kt+1). B margin ~1.5 iters.

typedef __bf16 bf16;
typedef __bf16 bf16x8 __attribute__((ext_vector_type(8)));
typedef float f32x4 __attribute__((ext_vector_type(4)));

#define MFMA16(a, b, c) __builtin_amdgcn_mfma_f32_16x16x32_bf16(a, b, c, 0, 0, 0)
#define BARRIER() asm volatile("s_barrier" ::: "memory")
#define VMCNT6() asm volatile("s_waitcnt vmcnt(6)" ::: "memory")
#define VMCNT4() asm volatile("s_waitcnt vmcnt(4)" ::: "memory")
#define VMCNT0() asm volatile("s_waitcnt vmcnt(0)" ::: "memory")
#define LGKM0()                                        \
  do {                                                 \
    asm volatile("s_waitcnt lgkmcnt(0)" ::: "memory"); \
    __builtin_amdgcn_sched_barrier(0);                 \
  } while (0)

__device__ __forceinline__ bf16x8 ld8(const bf16* p) { return *(const bf16x8*)p; }

__device__ __forceinline__ void gload16(const void* g, void* l) {
  __builtin_amdgcn_global_load_lds((__attribute__((address_space(1))) void*)(g),
                                   (__attribute__((address_space(3))) void*)(l), 16, 0, 0);
}

__device__ __forceinline__ int swz4(int row) { return (row ^ (row >> 2)) & 3; }

// ---------------- 1. weights f32 -> bf16 + zero M ----------------
__global__ __launch_bounds__(256) void wcvt_kernel(
    const float* __restrict__ wq, const float* __restrict__ wk, const float* __restrict__ wv,
    bf16* __restrict__ dst, float* __restrict__ Mz) {
  const int bid = blockIdx.x;
  if (bid >= 1536) {  // zero M: 64 blocks x 256 thr x 8 f32
    float* p = Mz + (size_t)(bid - 1536) * 2048 + threadIdx.x * 8;
    *(f32x4*)p = f32x4{0.f, 0.f, 0.f, 0.f};
    *(f32x4*)(p + 4) = f32x4{0.f, 0.f, 0.f, 0.f};
    return;
  }
  const int y = bid >> 9, x = bid & 511;
  const float* s = (y == 0) ? wq : (y == 1 ? wk : wv);
  const size_t i = ((size_t)x * 256 + threadIdx.x) * 8;
  f32x4 a = *(const f32x4*)(s + i);
  f32x4 b = *(const f32x4*)(s + i + 4);
  bf16x8 o;
  o[0] = (bf16)a[0]; o[1] = (bf16)a[1]; o[2] = (bf16)a[2]; o[3] = (bf16)a[3];
  o[4] = (bf16)b[0]; o[5] = (bf16)b[1]; o[6] = (bf16)b[2]; o[7] = (bf16)b[3];
  *(bf16x8*)(dst + (size_t)y * 1048576u + i) = o;
}

// ---------------- 2. QKV proj: C = A(f32)@W^T + bias, cvt fused ----------------
// 128x128 tile, BK=32, 4 waves (2x2, 64x64 each). A: reg-staged f32->bf16 ring-3
// (bufs 0/8K/16K). B: global_load_lds ring-3 (24K+{0,8K,16K}). 48KB -> 3 blk/CU.
__global__ __launch_bounds__(256, 3) void gemm_proj_a(
    const float* __restrict__ q, const float* __restrict__ k, const float* __restrict__ v,
    const bf16* __restrict__ Wall,
    const float* __restrict__ bq, const float* __restrict__ bk, const float* __restrict__ bv,
    bf16* __restrict__ Call) {
  __shared__ __align__(1024) char lds[49152];
  const int wg = blockIdx.x;                   // 768 = 96 mt x 8 nt
  const int swz = (wg & 7) * 96 + (wg >> 3);   // XCD-chunked, bijective (768%8==0)
  const int mt = swz >> 3, nt = swz & 7;
  const int z = mt >> 5;
  const int mloc = (mt & 31) * 128;
  const int n0 = nt * 128;
  const float* As = (z == 0) ? q : (z == 1 ? k : v);
  const bf16* W = Wall + (size_t)z * 1048576u + (size_t)n0 * 1024;

  const int t = threadIdx.x;
  const int lane = t & 63, wid = t >> 6;
  const int wr = wid >> 1, wc = wid & 1;
  const int r16 = lane & 15, kg = lane >> 4;

  int aoff[4], boff[4];
#pragma unroll
  for (int i = 0; i < 4; i++) {
    const int arow = wr * 64 + i * 16 + r16;
    aoff[i] = arow * 64 + ((kg ^ swz4(arow)) << 4);
    const int brow = wc * 64 + i * 16 + r16;
    boff[i] = brow * 64 + ((kg ^ swz4(brow)) << 4);
  }

  // A reg-staging: thread t covers row ar = t>>1, f32 cols (t&1)*16 .. +16
  const int ar = t >> 1;
  const float* Arow = As + (size_t)(mloc + ar) * 1024 + (t & 1) * 16;
  const int ws0 = ar * 64 + (((((t & 1) << 1) | 0) ^ swz4(ar)) << 4);
  const int ws1 = ar * 64 + (((((t & 1) << 1) | 1) ^ swz4(ar)) << 4);

  // B staging via gload16: chunks t and t+256 (row=c>>2, slot=c&3, pre-swizzled src)
  const int c1 = t, c2 = t + 256;
  const bf16* pb1 = W + (size_t)(c1 >> 2) * 1024 + ((c1 & 3) ^ swz4(c1 >> 2)) * 8;
  const bf16* pb2 = W + (size_t)(c2 >> 2) * 1024 + ((c2 & 3) ^ swz4(c2 >> 2)) * 8;
  const int bd1 = wid << 10, bd2 = 4096 + (wid << 10);

  f32x4 rg0, rg1, rg2, rg3;
  f32x4 acc[4][4] = {};

  // prologue. vmem issue order: A(0)x4, B(0)x2, B(1)x2, [implicit vmcnt(4) @write], A(1)x4
  {
    const float* p = Arow;
    rg0 = *(const f32x4*)p; rg1 = *(const f32x4*)(p + 4);
    rg2 = *(const f32x4*)(p + 8); rg3 = *(const f32x4*)(p + 12);
  }
  __builtin_amdgcn_sched_barrier(0);
  gload16(pb1, lds + 24576 + bd1);
  gload16(pb2, lds + 24576 + bd2);
  gload16(pb1 + 32, lds + 24576 + 8192 + bd1);
  gload16(pb2 + 32, lds + 24576 + 8192 + bd2);
  {
    bf16x8 p0, p1;
    p0[0] = (bf16)rg0[0]; p0[1] = (bf16)rg0[1]; p0[2] = (bf16)rg0[2]; p0[3] = (bf16)rg0[3];
    p0[4] = (bf16)rg1[0]; p0[5] = (bf16)rg1[1]; p0[6] = (bf16)rg1[2]; p0[7] = (bf16)rg1[3];
    p1[0] = (bf16)rg2[0]; p1[1] = (bf16)rg2[1]; p1[2] = (bf16)rg2[2]; p1[3] = (bf16)rg2[3];
    p1[4] = (bf16)rg3[0]; p1[5] = (bf16)rg3[1]; p1[6] = (bf16)rg3[2]; p1[7] = (bf16)rg3[3];
    *(bf16x8*)(lds + ws0) = p0;
    *(bf16x8*)(lds + ws1) = p1;
  }
  {
    const float* p = Arow + 32;
    rg0 = *(const f32x4*)p; rg1 = *(const f32x4*)(p + 4);
    rg2 = *(const f32x4*)(p + 8); rg3 = *(const f32x4*)(p + 12);
  }
  LGKM0();   // A(0) ds_writes drained
  VMCNT6();  // retire B(0); leaves B(1)x2 + A(1)x4 in flight
  BARRIER();

  int cb = 0;  // ring-3 buffer index
  for (int kt = 0; kt < 32; ++kt) {
    const char* la = lds + cb * 8192;
    const char* lb = lds + 24576 + cb * 8192;
    bf16x8 av[4], bw[4];
#pragma unroll
    for (int i = 0; i < 4; i++) av[i] = *(const bf16x8*)(la + aoff[i]);
#pragma unroll
    for (int j = 0; j < 4; j++) bw[j] = *(const bf16x8*)(lb + boff[j]);

    const int nb = (cb == 2) ? 0 : cb + 1;   // buf for tile kt+1 (A write)
    const int pbuf = (nb == 2) ? 0 : nb + 1; // buf for tile kt+2 (B gload)
    if (kt < 31) {  // ds_write A(kt+1); implicit wait vmcnt(2) (A(kt+1) regs), B stays
      bf16x8 p0, p1;
      p0[0] = (bf16)rg0[0]; p0[1] = (bf16)rg0[1]; p0[2] = (bf16)rg0[2]; p0[3] = (bf16)rg0[3];
      p0[4] = (bf16)rg1[0]; p0[5] = (bf16)rg1[1]; p0[6] = (bf16)rg1[2]; p0[7] = (bf16)rg1[3];
      p1[0] = (bf16)rg2[0]; p1[1] = (bf16)rg2[1]; p1[2] = (bf16)rg2[2]; p1[3] = (bf16)rg2[3];
      p1[4] = (bf16)rg3[0]; p1[5] = (bf16)rg3[1]; p1[6] = (bf16)rg3[2]; p1[7] = (bf16)rg3[3];
      *(bf16x8*)(lds + nb * 8192 + ws0) = p0;
      *(bf16x8*)(lds + nb * 8192 + ws1) = p1;
    }
    if (kt < 30) {  // prefetch tile kt+2: A regs FIRST, then B gloads (order pinned)
      const float* p = Arow + (kt + 2) * 32;
      rg0 = *(const f32x4*)p; rg1 = *(const f32x4*)(p + 4);
      rg2 = *(const f32x4*)(p + 8); rg3 = *(const f32x4*)(p + 12);
      __builtin_amdgcn_sched_barrier(0);
      gload16(pb1 + (kt + 2) * 32, lds + 24576 + pbuf * 8192 + bd1);
      gload16(pb2 + (kt + 2) * 32, lds + 24576 + pbuf * 8192 + bd2);
    }
    __builtin_amdgcn_s_setprio(1);
#pragma unroll
    for (int i = 0; i < 4; i++)
#pragma unroll
      for (int j = 0; j < 4; j++) acc[i][j] = MFMA16(av[i], bw[j], acc[i][j]);
    __builtin_amdgcn_s_setprio(0);
    LGKM0();  // ds_writes drained before barrier
    if (kt < 30) { VMCNT6(); BARRIER(); }       // retires B(kt+1); 6 newest stay in flight
    else if (kt == 30) { VMCNT0(); BARRIER(); } // B(31) landed
    cb = nb;
  }

  const float* bias = (z == 0) ? bq : (z == 1 ? bk : bv);
  bf16* C = Call + (size_t)z * 4194304u;
#pragma unroll
  for (int j = 0; j < 4; j++) {
    const int col = n0 + wc * 64 + j * 16 + r16;
    const float bj = bias[col];
#pragma unroll
    for (int i = 0; i < 4; i++) {
      const int row = mloc + wr * 64 + i * 16 + kg * 4;
#pragma unroll
      for (int r = 0; r < 4; r++)
        C[(size_t)(row + r) * 1024 + col] = (bf16)(acc[i][j][r] + bj);
    }
  }
}

// ---------------- ring-3 bf16 GEMM loop (gemm_out) ----------------
__device__ __forceinline__ void compute16(const char* la, const char* lb,
                                          const int aoff[4], const int boff[4],
                                          f32x4 (&acc)[4][4]) {
  bf16x8 av[4], bv[4];
#pragma unroll
  for (int i = 0; i < 4; i++) av[i] = *(const bf16x8*)(la + aoff[i]);
#pragma unroll
  for (int j = 0; j < 4; j++) bv[j] = *(const bf16x8*)(lb + boff[j]);
  __builtin_amdgcn_s_setprio(1);
#pragma unroll
  for (int i = 0; i < 4; i++)
#pragma unroll
    for (int j = 0; j < 4; j++) acc[i][j] = MFMA16(av[i], bv[j], acc[i][j]);
  __builtin_amdgcn_s_setprio(0);
}

__device__ __forceinline__ void ring128(const bf16* __restrict__ A, const bf16* __restrict__ B,
                                        char* lds, f32x4 (&acc)[4][4]) {
  const int t = threadIdx.x;
  const int lane = t & 63, wid = t >> 6;
  const int wr = wid >> 1, wc = wid & 1;
  const int r16 = lane & 15, kg = lane >> 4;

  int aoff[4], boff[4];
#pragma unroll
  for (int i = 0; i < 4; i++) {
    int row = wr * 64 + i * 16 + r16;
    aoff[i] = row * 64 + ((kg ^ swz4(row)) << 4);
    row = wc * 64 + i * 16 + r16;
    boff[i] = 8192 + row * 64 + ((kg ^ swz4(row)) << 4);
  }

  const int r1 = t >> 2, c = t & 3, r2 = r1 + 64;
  const bf16* pa1 = A + (size_t)r1 * 1024 + (c ^ swz4(r1)) * 8;
  const bf16* pa2 = A + (size_t)r2 * 1024 + (c ^ swz4(r2)) * 8;
  const bf16* pb1 = B + (size_t)r1 * 1024 + (c ^ swz4(r1)) * 8;
  const bf16* pb2 = B + (size_t)r2 * 1024 + (c ^ swz4(r2)) * 8;
  const int d1 = wid << 10, d2 = 4096 + (wid << 10);

#pragma unroll
  for (int p = 0; p < 2; p++) {
    char* d = lds + p * 16384;
    gload16(pa1 + p * 32, d + d1);
    gload16(pa2 + p * 32, d + d2);
    gload16(pb1 + p * 32, d + 8192 + d1);
    gload16(pb2 + p * 32, d + 8192 + d2);
  }
  pa1 += 64; pa2 += 64; pb1 += 64; pb2 += 64;

  int cb = 0, rb = 2;
  for (int kt = 0; kt < 30; kt++) {
    VMCNT4();
    BARRIER();
    {
      char* d = lds + rb * 16384;
      gload16(pa1, d + d1);
      gload16(pa2, d + d2);
      gload16(pb1, d + 8192 + d1);
      gload16(pb2, d + 8192 + d2);
      pa1 += 32; pa2 += 32; pb1 += 32; pb2 += 32;
    }
    compute16(lds + cb * 16384, lds + cb * 16384, aoff, boff, acc);
    LGKM0();
    cb = (cb == 2) ? 0 : cb + 1;
    rb = (rb == 2) ? 0 : rb + 1;
  }
  VMCNT4();
  BARRIER();
  compute16(lds + cb * 16384, lds + cb * 16384, aoff, boff, acc);
  LGKM0();
  cb = (cb == 2) ? 0 : cb + 1;
  VMCNT0(); BARRIER();
  compute16(lds + cb * 16384, lds + cb * 16384, aoff, boff, acc);
}

// ---------------- 3. M[b,h][i][j] += sum_s K[s,i] * V[s,j] (4 subtiles/block) ----------------
__global__ __launch_bounds__(256) void ktv_kernel(
    const bf16* __restrict__ Kb, const bf16* __restrict__ Vb, float* __restrict__ M) {
  const int bh = blockIdx.x >> 2, sc = blockIdx.x & 3;
  const int b = bh >> 4, h = bh & 15;
  __shared__ bf16 Kl[64][136];
  __shared__ bf16 Vl[64][136];
  const int t = threadIdx.x;
  const int l = t & 63, w = t >> 6;
  const int r16 = l & 15, kg = l >> 4;
  f32x4 acc[4] = {};
  for (int sub = 0; sub < 4; ++sub) {
    const int s0 = sc * 512 + sub * 128;
    const size_t base = ((size_t)b * 2048 + s0) * 1024 + h * 64;
    if (sub) __syncthreads();
#pragma unroll
    for (int p = 0; p < 4; p++) {
      const int chunk = p * 256 + t;
      const int s = chunk >> 3, d0 = (chunk & 7) * 8;
      bf16x8 kv = ld8(Kb + base + (size_t)s * 1024 + d0);
      bf16x8 vv = ld8(Vb + base + (size_t)s * 1024 + d0);
#pragma unroll
      for (int e = 0; e < 8; e++) { Kl[d0 + e][s] = kv[e]; Vl[d0 + e][s] = vv[e]; }
    }
    __syncthreads();
#pragma unroll
    for (int ks = 0; ks < 4; ks++) {
      bf16x8 a = ld8(&Kl[w * 16 + r16][ks * 32 + kg * 8]);
#pragma unroll
      for (int j = 0; j < 4; j++) {
        bf16x8 bvv = ld8(&Vl[j * 16 + r16][ks * 32 + kg * 8]);
        acc[j] = MFMA16(a, bvv, acc[j]);
      }
    }
  }
  float* Mh = M + (size_t)bh * 4096;
#pragma unroll
  for (int j = 0; j < 4; j++)
#pragma unroll
    for (int r = 0; r < 4; r++)
      atomicAdd(&Mh[(w * 16 + kg * 4 + r) * 64 + j * 16 + r16], acc[j][r]);
}

// ---------------- 4. Gt[b][n][h*64+d'] = sum_d Wo[n,h*64+d](f32) * M_bh[d',d]/8 ----------------
__global__ __launch_bounds__(256) void gt_kernel(
    const float* __restrict__ Wo, const float* __restrict__ M, bf16* __restrict__ Gt) {
  const int bid = blockIdx.x;
  const int b = bid >> 7, h = (bid >> 3) & 15, nt = bid & 7;
  const int n0 = nt * 128;
  const float* Mh = M + (size_t)((b << 4) + h) * 4096;
  const int l = threadIdx.x & 63, w = threadIdx.x >> 6;
  const int r16 = l & 15, kg = l >> 4;
  f32x4 acc[2][4] = {};
#pragma unroll
  for (int kk = 0; kk < 2; kk++) {
    bf16x8 a[2];
#pragma unroll
    for (int i = 0; i < 2; i++) {
      const float* wp = Wo + (size_t)(n0 + w * 32 + i * 16 + r16) * 1024 + h * 64 + kk * 32 + kg * 8;
      f32x4 lo = *(const f32x4*)wp;
      f32x4 hi = *(const f32x4*)(wp + 4);
      a[i][0] = (bf16)lo[0]; a[i][1] = (bf16)lo[1]; a[i][2] = (bf16)lo[2]; a[i][3] = (bf16)lo[3];
      a[i][4] = (bf16)hi[0]; a[i][5] = (bf16)hi[1]; a[i][6] = (bf16)hi[2]; a[i][7] = (bf16)hi[3];
    }
#pragma unroll
    for (int j = 0; j < 4; j++) {
      const float* mp = Mh + (j * 16 + r16) * 64 + kk * 32 + kg * 8;
      f32x4 m0v = *(const f32x4*)mp;
      f32x4 m1v = *(const f32x4*)(mp + 4);
      bf16x8 bv;
      bv[0] = (bf16)(m0v[0] * 0.125f); bv[1] = (bf16)(m0v[1] * 0.125f);
      bv[2] = (bf16)(m0v[2] * 0.125f); bv[3] = (bf16)(m0v[3] * 0.125f);
      bv[4] = (bf16)(m1v[0] * 0.125f); bv[5] = (bf16)(m1v[1] * 0.125f);
      bv[6] = (bf16)(m1v[2] * 0.125f); bv[7] = (bf16)(m1v[3] * 0.125f);
#pragma unroll
      for (int i = 0; i < 2; i++) acc[i][j] = MFMA16(a[i], bv, acc[i][j]);
    }
  }
  bf16* G = Gt + (size_t)b * 1048576u;
#pragma unroll
  for (int i = 0; i < 2; i++)
#pragma unroll
    for (int j = 0; j < 4; j++)
#pragma unroll
      for (int r = 0; r < 4; r++)
        G[(size_t)(n0 + w * 32 + i * 16 + kg * 4 + r) * 1024 + h * 64 + j * 16 + r16] =
            (bf16)acc[i][j][r];
}

// ---------------- 5. x = resid + Q @ Gt_b^T + bo  -> bf16 ws ----------------
__global__ __launch_bounds__(256, 3) void gemm_out_r(
    const bf16* __restrict__ Q, const bf16* __restrict__ Gt,
    const float* __restrict__ bo, const float* __restrict__ resid, bf16* __restrict__ xb) {
  __shared__ __align__(1024) char lds[49152];
  const int wg = blockIdx.x;                 // 256 = 32 mt x 8 nt
  const int swz = (wg & 7) * 32 + (wg >> 3);
  const int mt = swz >> 3, nt = swz & 7;
  const int m0 = mt * 128, n0 = nt * 128;

  f32x4 acc[4][4] = {};
  ring128(Q + (size_t)m0 * 1024, Gt + (size_t)(m0 >> 11) * 1048576u + (size_t)n0 * 1024, lds, acc);

  const int lane = threadIdx.x & 63, wid = threadIdx.x >> 6;
  const int wr = wid >> 1, wc = wid & 1, r16 = lane & 15, kg = lane >> 4;
#pragma unroll
  for (int j = 0; j < 4; j++) {
    const int col = n0 + wc * 64 + j * 16 + r16;
    const float bj = bo[col];
#pragma unroll
    for (int i = 0; i < 4; i++) {
      const int row = m0 + wr * 64 + i * 16 + kg * 4;
#pragma unroll
      for (int r = 0; r < 4; r++) {
        const size_t off = (size_t)(row + r) * 1024 + col;
        xb[off] = (bf16)(acc[i][j][r] + bj + resid[off]);
      }
    }
  }
}

// ---------------- 6. LayerNorm: x bf16 -> out f32, one row per wave ----------------
__global__ __launch_bounds__(256) void ln_kernel(
    const bf16* __restrict__ xb, const float* __restrict__ g, const float* __restrict__ bb,
    float* __restrict__ out) {
  const int lane = threadIdx.x & 63, wid = threadIdx.x >> 6;
  const int row = (blockIdx.x << 2) + wid;
  const bf16* xr = xb + (size_t)row * 1024;
  bf16x8 h0 = ld8(xr + lane * 16);
  bf16x8 h1 = ld8(xr + lane * 16 + 8);
  float v[16];
#pragma unroll
  for (int e = 0; e < 8; e++) { v[e] = (float)h0[e]; v[8 + e] = (float)h1[e]; }
  float s = 0.f, s2 = 0.f;
#pragma unroll
  for (int e = 0; e < 16; e++) { s += v[e]; s2 += v[e] * v[e]; }
#pragma unroll
  for (int m = 32; m; m >>= 1) { s += __shfl_xor(s, m); s2 += __shfl_xor(s2, m); }
  const float mu = s * (1.0f / 1024.0f);
  const float rstd = rsqrtf(s2 * (1.0f / 1024.0f) - mu * mu + 1e-5f);
  float* orow = out + (size_t)row * 1024 + lane * 16;
#pragma unroll
  for (int e = 0; e < 4; e++) {
    f32x4 gg = *(const f32x4*)(g + lane * 16 + e * 4);
    f32x4 bv = *(const f32x4*)(bb + lane * 16 + e * 4);
    f32x4 o;
#pragma unroll
    for (int u = 0; u < 4; u++) o[u] = gg[u] * ((v[e * 4 + u] - mu) * rstd) + bv[u];
    *(f32x4*)(orow + e * 4) = o;
  }
}

extern "C" void kernel_launch(void* const* d_in, const int* in_sizes, int n_in,
                              void* d_out, int out_size, void* d_ws, size_t ws_size,
                              hipStream_t stream) {
  (void)in_sizes; (void)n_in; (void)out_size; (void)ws_size;
  const float* q    = (const float*)d_in[0];
  const float* k    = (const float*)d_in[1];
  const float* v    = (const float*)d_in[2];
  // d_in[3]=mask (all False), d_in[4]=training: unused
  const float* wq_w = (const float*)d_in[5];
  const float* wq_b = (const float*)d_in[6];
  const float* wk_w = (const float*)d_in[7];
  const float* wk_b = (const float*)d_in[8];
  const float* wv_w = (const float*)d_in[9];
  const float* wv_b = (const float*)d_in[10];
  const float* wo_w = (const float*)d_in[11];
  const float* wo_b = (const float*)d_in[12];
  const float* ln_g = (const float*)d_in[13];
  const float* ln_b = (const float*)d_in[14];
  float* out = (float*)d_out;

  bf16* wsb    = (bf16*)d_ws;
  bf16* w_bf   = wsb;                        // [0, 3145728) Wq,Wk,Wv bf16
  bf16* QKV_bf = wsb + 3145728u;             // Q,K,V bf16
  float* M     = (float*)(wsb + 15728640u);  // 131072 f32 (512 KiB)
  bf16* Gt     = wsb + 15990784u;            // 2,097,152 elems
  bf16* xb     = wsb + 18087936u;            // 4,194,304 elems (pre-LN x, bf16)

  wcvt_kernel<<<1600, 256, 0, stream>>>(wq_w, wk_w, wv_w, w_bf, M);
  gemm_proj_a<<<768, 256, 0, stream>>>(q, k, v, w_bf, wq_b, wk_b, wv_b, QKV_bf);
  ktv_kernel<<<128, 256, 0, stream>>>(QKV_bf + 4194304u, QKV_bf + 8388608u, M);
  gt_kernel<<<256, 256, 0, stream>>>(wo_w, M, Gt);
  gemm_out_r<<<256, 256, 0, stream>>>(QKV_bf, Gt, wo_b, q, xb);
  ln_kernel<<<1024, 256, 0, stream>>>(xb, ln_g, ln_b, out);
}